// Round 1
// baseline (2133.870 us; speedup 1.0000x reference)
//
#include <hip/hip_runtime.h>

typedef _Float16 f16;
typedef _Float16 f16x8 __attribute__((ext_vector_type(8)));
typedef float f32x4 __attribute__((ext_vector_type(4)));
typedef unsigned int u32;
typedef u32 u32x4 __attribute__((ext_vector_type(4)));

#define NB 16
#define LX 2048
#define LY 2048
#define KD 1024
#define OD 1024

#define MFMA16(a, b, c) __builtin_amdgcn_mfma_f32_16x16x32_f16(a, b, c, 0, 0, 0)

// ---------------- f32 -> f16 elementwise convert ----------------
__global__ void k_cvt(const float* __restrict__ in, f16* __restrict__ out, int n8) {
  int idx = blockIdx.x * blockDim.x + threadIdx.x;
  int stride = gridDim.x * blockDim.x;
  for (int i = idx; i < n8; i += stride) {
    const float4* p = (const float4*)(in + (size_t)i * 8);
    float4 a = p[0], b = p[1];
    f16x8 o;
    o[0] = (f16)a.x; o[1] = (f16)a.y; o[2] = (f16)a.z; o[3] = (f16)a.w;
    o[4] = (f16)b.x; o[5] = (f16)b.y; o[6] = (f16)b.z; o[7] = (f16)b.w;
    *(f16x8*)(out + (size_t)i * 8) = o;
  }
}

// ------------- W[k][n] f32  ->  Wt[n][k] f16 (transpose + convert) -------------
__global__ void k_wtrans(const float* __restrict__ W, f16* __restrict__ Wt) {
  __shared__ float t[32][33];
  int k0 = blockIdx.x * 32, n0 = blockIdx.y * 32;
  int tx = threadIdx.x & 31, ty = threadIdx.x >> 5;  // 32 x 8
#pragma unroll
  for (int r = 0; r < 32; r += 8)
    t[ty + r][tx] = W[(size_t)(k0 + ty + r) * 1024 + n0 + tx];
  __syncthreads();
#pragma unroll
  for (int r = 0; r < 32; r += 8)
    Wt[(size_t)(n0 + ty + r) * 1024 + k0 + tx] = (f16)t[tx][ty + r];
}

// ---------------- projection GEMM: C = relu(A*W + bias), fp16 out ----------------
// A: (M=32768, 1024) f16 row-major.  Bt: (1024 n, 1024 k) f16 (W transposed).
// TOUT=false: C[m][n] row-major.  TOUT=true: C is Vt[(b*1024 + n)][key] with m=(b,key).
template <bool TOUT>
__global__ __launch_bounds__(256) void k_gemm(const f16* __restrict__ A,
                                              const f16* __restrict__ Bt,
                                              const float* __restrict__ bias,
                                              f16* __restrict__ C) {
  const int m0 = blockIdx.x * 128, n0 = blockIdx.y * 128;
  const int tid = threadIdx.x;
  const int lane = tid & 63;
  const int wave = tid >> 6;
  const int lr = lane & 15, lg = lane >> 4;
  const int wm = (wave >> 1) * 64, wn = (wave & 1) * 64;

  __shared__ f16 Al[2][4096];  // [g:4][row:128][8]
  __shared__ f16 Bl[2][4096];
  __shared__ f16 Ct[TOUT ? 128 * 136 : 1];

  f32x4 acc[4][4] = {};

  const int slot0 = tid, slot1 = tid + 256;
  const int g0 = slot0 >> 7, r0 = slot0 & 127;
  const int g1 = slot1 >> 7, r1 = slot1 & 127;
  const f16* Arow0 = A + (size_t)(m0 + r0) * 1024 + g0 * 8;
  const f16* Arow1 = A + (size_t)(m0 + r1) * 1024 + g1 * 8;
  const f16* Brow0 = Bt + (size_t)(n0 + r0) * 1024 + g0 * 8;
  const f16* Brow1 = Bt + (size_t)(n0 + r1) * 1024 + g1 * 8;

  u32x4 ra0, ra1, rb0, rb1;
  ra0 = *(const u32x4*)(Arow0);
  ra1 = *(const u32x4*)(Arow1);
  rb0 = *(const u32x4*)(Brow0);
  rb1 = *(const u32x4*)(Brow1);
  *(u32x4*)(&Al[0][slot0 * 8]) = ra0;
  *(u32x4*)(&Al[0][slot1 * 8]) = ra1;
  *(u32x4*)(&Bl[0][slot0 * 8]) = rb0;
  *(u32x4*)(&Bl[0][slot1 * 8]) = rb1;

  for (int t = 0; t < 32; ++t) {
    __syncthreads();
    if (t + 1 < 32) {
      ra0 = *(const u32x4*)(Arow0 + (t + 1) * 32);
      ra1 = *(const u32x4*)(Arow1 + (t + 1) * 32);
      rb0 = *(const u32x4*)(Brow0 + (t + 1) * 32);
      rb1 = *(const u32x4*)(Brow1 + (t + 1) * 32);
    }
    const int buf = t & 1;
    f16x8 af[4], bf[4];
#pragma unroll
    for (int mi = 0; mi < 4; mi++)
      af[mi] = *(const f16x8*)(&Al[buf][(lg * 128 + wm + mi * 16 + lr) * 8]);
#pragma unroll
    for (int ni = 0; ni < 4; ni++)
      bf[ni] = *(const f16x8*)(&Bl[buf][(lg * 128 + wn + ni * 16 + lr) * 8]);
#pragma unroll
    for (int mi = 0; mi < 4; mi++)
#pragma unroll
      for (int ni = 0; ni < 4; ni++)
        acc[mi][ni] = MFMA16(af[mi], bf[ni], acc[mi][ni]);
    if (t + 1 < 32) {
      const int nb = (t + 1) & 1;
      *(u32x4*)(&Al[nb][slot0 * 8]) = ra0;
      *(u32x4*)(&Al[nb][slot1 * 8]) = ra1;
      *(u32x4*)(&Bl[nb][slot0 * 8]) = rb0;
      *(u32x4*)(&Bl[nb][slot1 * 8]) = rb1;
    }
  }

  if constexpr (!TOUT) {
#pragma unroll
    for (int ni = 0; ni < 4; ni++) {
      float bb = bias[n0 + wn + ni * 16 + lr];
#pragma unroll
      for (int mi = 0; mi < 4; mi++) {
#pragma unroll
        for (int i = 0; i < 4; i++) {
          int row = m0 + wm + mi * 16 + lg * 4 + i;
          float v = fmaxf(acc[mi][ni][i] + bb, 0.f);
          C[(size_t)row * 1024 + n0 + wn + ni * 16 + lr] = (f16)v;
        }
      }
    }
  } else {
    // stage tile transposed in LDS, then write Vt coalesced along key
#pragma unroll
    for (int ni = 0; ni < 4; ni++) {
      float bb = bias[n0 + wn + ni * 16 + lr];
      int od = wn + ni * 16 + lr;
#pragma unroll
      for (int mi = 0; mi < 4; mi++) {
#pragma unroll
        for (int i = 0; i < 4; i++) {
          int key = wm + mi * 16 + lg * 4 + i;
          float v = fmaxf(acc[mi][ni][i] + bb, 0.f);
          Ct[od * 136 + key] = (f16)v;
        }
      }
    }
    __syncthreads();
    const int bb_ = m0 >> 11;       // batch
    const int key0 = m0 & 2047;     // key within batch
#pragma unroll
    for (int i = 0; i < 8; i++) {
      int slot = tid + i * 256;     // 2048 slots: od(128) x k8(16)
      int od = slot >> 4, k8 = slot & 15;
      f16x8 v = *(const f16x8*)(&Ct[od * 136 + k8 * 8]);
      *(f16x8*)(C + ((size_t)(bb_ * 1024 + n0 + od)) * 2048 + key0 + k8 * 8) = v;
    }
  }
}

// ---------------- fused flash attention ----------------
// Qh: (B, LX, 1024) f16.  Kh: (B, LY, 1024) f16.  Vt: (B, 1024, LY) f16.
// mask: (B, LY) int, nonzero = masked (-inf).  out: (B, LX, 1024) f32.
__global__ __launch_bounds__(512) void k_flash(const f16* __restrict__ Qh,
                                               const f16* __restrict__ Kh,
                                               const f16* __restrict__ Vt,
                                               const int* __restrict__ mask,
                                               float* __restrict__ out) {
  const int bid = blockIdx.x;
  const int b = bid >> 6;
  const int q0 = (bid & 63) << 5;
  const int tid = threadIdx.x;
  const int wave = tid >> 6, lane = tid & 63;
  const int lr = lane & 15, lg = lane >> 4;

  __shared__ f16 Qs[32768];  // [g:128][row:32][8]  = 64 KB
  __shared__ f16 Ps[4096];   // [kg:16][row:32][8]  = 8 KB
  __shared__ float pmax[8][32];
  __shared__ float psum[8][32];
  __shared__ float m_s[32], l_s[32], sc_s[32];

  const f16* Qb = Qh + ((size_t)b * LX + q0) * 1024;
#pragma unroll
  for (int i = 0; i < 8; ++i) {
    int slot = tid + i * 512;  // 4096 slots: g*32 + row
    int row = slot & 31, g = slot >> 5;
    *(u32x4*)(&Qs[slot * 8]) = *(const u32x4*)(Qb + (size_t)row * 1024 + g * 8);
  }
  if (tid < 32) {
    m_s[tid] = -1e30f;
    l_s[tid] = 0.f;
  }
  __syncthreads();

  f32x4 acc[2][8] = {};
  const f16* Kb = Kh + (size_t)b * LY * 1024;
  const f16* Vb = Vt + (size_t)b * 1024 * LY;
  const int* mb = mask + b * LY;

  for (int kt = 0; kt < LY / 128; ++kt) {
    const int keyl = (wave << 4) + lr;        // key within tile (wave owns 16 keys)
    const int key = (kt << 7) + keyl;
    f32x4 s0 = {0.f, 0.f, 0.f, 0.f}, s1 = {0.f, 0.f, 0.f, 0.f};
    const f16* Kr = Kb + (size_t)key * 1024 + lg * 8;
#pragma unroll
    for (int ks = 0; ks < 32; ++ks) {
      f16x8 kf = *(const f16x8*)(Kr + ks * 32);
      f16x8 a0 = *(const f16x8*)(&Qs[((ks * 4 + lg) * 32 + lr) * 8]);
      f16x8 a1 = *(const f16x8*)(&Qs[((ks * 4 + lg) * 32 + 16 + lr) * 8]);
      s0 = MFMA16(a0, kf, s0);
      s1 = MFMA16(a1, kf, s1);
    }
    if (mb[key] != 0) {
#pragma unroll
      for (int i = 0; i < 4; i++) {
        s0[i] = -1e30f;
        s1[i] = -1e30f;
      }
    }
    // per-row partial max over this wave's 16 keys
#pragma unroll
    for (int f = 0; f < 2; ++f) {
#pragma unroll
      for (int i = 0; i < 4; i++) {
        float v = f ? s1[i] : s0[i];
        v = fmaxf(v, __shfl_xor(v, 1));
        v = fmaxf(v, __shfl_xor(v, 2));
        v = fmaxf(v, __shfl_xor(v, 4));
        v = fmaxf(v, __shfl_xor(v, 8));
        if (lr == 0) pmax[wave][f * 16 + lg * 4 + i] = v;
      }
    }
    __syncthreads();
    if (tid < 32) {
      float mx = pmax[0][tid];
#pragma unroll
      for (int w = 1; w < 8; w++) mx = fmaxf(mx, pmax[w][tid]);
      float mo = m_s[tid];
      float mn = fmaxf(mo, mx);
      m_s[tid] = mn;
      sc_s[tid] = __expf(mo - mn);
    }
    __syncthreads();
    // p = exp(s - m), partial row sums, stage P as fp16 for PV
#pragma unroll
    for (int f = 0; f < 2; ++f) {
#pragma unroll
      for (int i = 0; i < 4; i++) {
        int row = f * 16 + lg * 4 + i;
        float sv = f ? s1[i] : s0[i];
        float p = (sv < -5e29f) ? 0.f : __expf(sv - m_s[row]);
        float t = p;
        t += __shfl_xor(t, 1);
        t += __shfl_xor(t, 2);
        t += __shfl_xor(t, 4);
        t += __shfl_xor(t, 8);
        if (lr == 0) psum[wave][row] = t;
        Ps[((keyl >> 3) * 32 + row) * 8 + (keyl & 7)] = (f16)p;
      }
    }
    __syncthreads();
    if (tid < 32) {
      float t = psum[0][tid];
#pragma unroll
      for (int w = 1; w < 8; w++) t += psum[w][tid];
      l_s[tid] = l_s[tid] * sc_s[tid] + t;
    }
    // rescale accumulator
#pragma unroll
    for (int f = 0; f < 2; ++f)
#pragma unroll
      for (int i = 0; i < 4; i++) {
        float scv = sc_s[f * 16 + lg * 4 + i];
#pragma unroll
        for (int o = 0; o < 8; o++) acc[f][o][i] *= scv;
      }
    // PV: wave owns od slice [wave*128, wave*128+128)
    const f16* Vw = Vb + (size_t)(wave * 128) * LY + (kt << 7) + lg * 8;
#pragma unroll
    for (int kk = 0; kk < 4; ++kk) {
      f16x8 pa0 = *(const f16x8*)(&Ps[((kk * 4 + lg) * 32 + lr) * 8]);
      f16x8 pa1 = *(const f16x8*)(&Ps[((kk * 4 + lg) * 32 + 16 + lr) * 8]);
#pragma unroll
      for (int o = 0; o < 8; o++) {
        f16x8 vf = *(const f16x8*)(Vw + (size_t)(o * 16 + lr) * LY + kk * 32);
        acc[0][o] = MFMA16(pa0, vf, acc[0][o]);
        acc[1][o] = MFMA16(pa1, vf, acc[1][o]);
      }
    }
  }
  __syncthreads();
  float* ob = out + ((size_t)b * LX + q0) * 1024 + wave * 128;
#pragma unroll
  for (int f = 0; f < 2; ++f)
#pragma unroll
    for (int i = 0; i < 4; i++) {
      int row = f * 16 + lg * 4 + i;
      float inv = 1.f / l_s[row];
#pragma unroll
      for (int o = 0; o < 8; o++)
        ob[(size_t)row * 1024 + o * 16 + lr] = acc[f][o][i] * inv;
    }
}

extern "C" void kernel_launch(void* const* d_in, const int* in_sizes, int n_in,
                              void* d_out, int out_size, void* d_ws, size_t ws_size,
                              hipStream_t stream) {
  const float* x = (const float*)d_in[0];
  const float* y = (const float*)d_in[1];
  const int* ym = (const int*)d_in[2];
  const float* Wq = (const float*)d_in[3];
  const float* bq = (const float*)d_in[4];
  const float* Wk = (const float*)d_in[5];
  const float* bk = (const float*)d_in[6];
  const float* Wv = (const float*)d_in[7];
  const float* bv = (const float*)d_in[8];
  float* out = (float*)d_out;

  char* w = (char*)d_ws;
  const size_t SZ_T = (size_t)NB * LX * KD * sizeof(f16);  // 64 MB
  const size_t SZ_W = (size_t)KD * OD * sizeof(f16);       // 2 MB
  f16* xh = (f16*)(w);
  f16* yh = (f16*)(w + SZ_T);
  f16* Wqt = (f16*)(w + 2 * SZ_T);
  f16* Wkt = (f16*)(w + 2 * SZ_T + SZ_W);
  f16* Wvt = (f16*)(w + 2 * SZ_T + 2 * SZ_W);
  f16* Qhp = (f16*)(w + 2 * SZ_T + 3 * SZ_W);
  f16* Khp = (f16*)(w + 3 * SZ_T + 3 * SZ_W);
  f16* Vtp = (f16*)(w + 4 * SZ_T + 3 * SZ_W);

  k_cvt<<<2048, 256, 0, stream>>>(x, xh, NB * LX * KD / 8);
  k_cvt<<<2048, 256, 0, stream>>>(y, yh, NB * LY * KD / 8);
  dim3 wt(32, 32);
  k_wtrans<<<wt, 256, 0, stream>>>(Wq, Wqt);
  k_wtrans<<<wt, 256, 0, stream>>>(Wk, Wkt);
  k_wtrans<<<wt, 256, 0, stream>>>(Wv, Wvt);
  dim3 gg(256, 8);
  k_gemm<false><<<gg, 256, 0, stream>>>(xh, Wqt, bq, Qhp);
  k_gemm<false><<<gg, 256, 0, stream>>>(yh, Wkt, bk, Khp);
  k_gemm<true><<<gg, 256, 0, stream>>>(yh, Wvt, bv, Vtp);
  k_flash<<<NB * (LX / 32), 512, 0, stream>>>(Qhp, Khp, Vtp, ym, out);
}

// Round 3
// 1517.942 us; speedup vs baseline: 1.4058x; 1.4058x over previous
//
#include <hip/hip_runtime.h>

typedef _Float16 f16;
typedef _Float16 f16x8 __attribute__((ext_vector_type(8)));
typedef _Float16 f16x4 __attribute__((ext_vector_type(4)));
typedef float f32x4 __attribute__((ext_vector_type(4)));
typedef unsigned int u32;
typedef u32 u32x4 __attribute__((ext_vector_type(4)));

#define NB 16
#define LSEQ 2048
#define DIM 1024
#define CHB 8  // batches per attention chunk (S chunk = CHB*16MB = 128MB)

#define MFMA16(a, b, c) __builtin_amdgcn_mfma_f32_16x16x32_f16(a, b, c, 0, 0, 0)

typedef const __attribute__((address_space(1))) void glb_t;
typedef __attribute__((address_space(3))) void lds_t;
__device__ __forceinline__ void ld_lds16(const void* g, void* l) {
  __builtin_amdgcn_global_load_lds((glb_t*)g, (lds_t*)l, 16, 0, 0);
}

// ---------------- f32 -> f16 elementwise convert ----------------
__global__ void k_cvt(const float* __restrict__ in, f16* __restrict__ out, int n8) {
  int idx = blockIdx.x * blockDim.x + threadIdx.x;
  int stride = gridDim.x * blockDim.x;
  for (int i = idx; i < n8; i += stride) {
    const float4* p = (const float4*)(in + (size_t)i * 8);
    float4 a = p[0], b = p[1];
    f16x8 o;
    o[0] = (f16)a.x; o[1] = (f16)a.y; o[2] = (f16)a.z; o[3] = (f16)a.w;
    o[4] = (f16)b.x; o[5] = (f16)b.y; o[6] = (f16)b.z; o[7] = (f16)b.w;
    *(f16x8*)(out + (size_t)i * 8) = o;
  }
}

// ------------- W[k][n] f32 -> Wt[n][k] f16 (transpose + convert) -------------
__global__ void k_wtrans(const float* __restrict__ W, f16* __restrict__ Wt) {
  __shared__ float t[32][33];
  int k0 = blockIdx.x * 32, n0 = blockIdx.y * 32;
  int tx = threadIdx.x & 31, ty = threadIdx.x >> 5;  // 32 x 8
#pragma unroll
  for (int r = 0; r < 32; r += 8)
    t[ty + r][tx] = W[(size_t)(k0 + ty + r) * 1024 + n0 + tx];
  __syncthreads();
#pragma unroll
  for (int r = 0; r < 32; r += 8)
    Wt[(size_t)(n0 + ty + r) * 1024 + k0 + tx] = (f16)t[tx][ty + r];
}

// ---------------- unified 128x128 GEMM, global_load_lds staging ----------------
// C = A (M x K) * Bt^T where Bt is (N x K) row-major over K. f32 accum.
// EPI 0: relu(acc + bias) -> f16 C row-major, ldc = 1024
// EPI 1: relu(acc + bias) -> f16 Vt[(batch*1024 + n)][key], via LDS transpose
// EPI 2: raw f32 -> C (runtime ldc)
template <int EPI, int NSTEP>
__global__ __launch_bounds__(256) void k_mm(
    const f16* __restrict__ A, int lda, size_t saz,
    const f16* __restrict__ Bt, int ldb, size_t sbz,
    const float* __restrict__ bias,
    void* __restrict__ Cv, int ldc, size_t scz) {
  const int m0 = blockIdx.x * 128, n0 = blockIdx.y * 128, bz = blockIdx.z;
  const int tid = threadIdx.x;
  const int lane = tid & 63, wave = tid >> 6;
  const int lr = lane & 15, lg = lane >> 4;
  const int wm = (wave >> 1) * 64, wn = (wave & 1) * 64;

  __shared__ f16 Al[2][4096];  // [g:4][row:128][8]
  __shared__ f16 Bl[2][4096];
  __shared__ f16 Ct[EPI == 1 ? 128 * 136 : 1];

  const int g0 = tid >> 7, r0 = tid & 127;
  const f16* pa = A + bz * saz + (size_t)(m0 + r0) * lda + g0 * 8;
  const f16* pb = Bt + bz * sbz + (size_t)(n0 + r0) * ldb + g0 * 8;

  // stage k-step 0 into buf 0
  ld_lds16(pa, &Al[0][tid * 8]);
  ld_lds16(pa + 16, &Al[0][(tid + 256) * 8]);
  ld_lds16(pb, &Bl[0][tid * 8]);
  ld_lds16(pb + 16, &Bl[0][(tid + 256) * 8]);

  f32x4 acc[4][4] = {};

  for (int t = 0; t < NSTEP; ++t) {
    __syncthreads();  // drains vmcnt -> buf[t&1] ready for everyone
    const int buf = t & 1;
    if (t + 1 < NSTEP) {
      const int nb = (t + 1) & 1;
      const f16* qa = pa + (t + 1) * 32;
      const f16* qb = pb + (t + 1) * 32;
      ld_lds16(qa, &Al[nb][tid * 8]);
      ld_lds16(qa + 16, &Al[nb][(tid + 256) * 8]);
      ld_lds16(qb, &Bl[nb][tid * 8]);
      ld_lds16(qb + 16, &Bl[nb][(tid + 256) * 8]);
    }
    f16x8 af[4], bf[4];
#pragma unroll
    for (int mi = 0; mi < 4; mi++)
      af[mi] = *(const f16x8*)(&Al[buf][(lg * 128 + wm + mi * 16 + lr) * 8]);
#pragma unroll
    for (int ni = 0; ni < 4; ni++)
      bf[ni] = *(const f16x8*)(&Bl[buf][(lg * 128 + wn + ni * 16 + lr) * 8]);
#pragma unroll
    for (int mi = 0; mi < 4; mi++)
#pragma unroll
      for (int ni = 0; ni < 4; ni++)
        acc[mi][ni] = MFMA16(af[mi], bf[ni], acc[mi][ni]);
  }

  if constexpr (EPI == 0) {
    f16* C = (f16*)Cv;
#pragma unroll
    for (int ni = 0; ni < 4; ni++) {
      float bb = bias[n0 + wn + ni * 16 + lr];
#pragma unroll
      for (int mi = 0; mi < 4; mi++)
#pragma unroll
        for (int i = 0; i < 4; i++) {
          int row = m0 + wm + mi * 16 + lg * 4 + i;
          float v = fmaxf(acc[mi][ni][i] + bb, 0.f);
          C[(size_t)row * 1024 + n0 + wn + ni * 16 + lr] = (f16)v;
        }
    }
  } else if constexpr (EPI == 1) {
    // stage tile transposed in LDS, then write Vt coalesced along key
#pragma unroll
    for (int ni = 0; ni < 4; ni++) {
      float bb = bias[n0 + wn + ni * 16 + lr];
      int od = wn + ni * 16 + lr;
#pragma unroll
      for (int mi = 0; mi < 4; mi++)
#pragma unroll
        for (int i = 0; i < 4; i++) {
          int key = wm + mi * 16 + lg * 4 + i;
          float v = fmaxf(acc[mi][ni][i] + bb, 0.f);
          Ct[od * 136 + key] = (f16)v;
        }
    }
    __syncthreads();
    f16* C = (f16*)Cv;
    const int bb_ = m0 >> 11;    // batch
    const int key0 = m0 & 2047;  // key within batch
#pragma unroll
    for (int i = 0; i < 8; i++) {
      int slot = tid + i * 256;  // 2048 slots: od(128) x k8(16)
      int od = slot >> 4, k8 = slot & 15;
      f16x8 v = *(const f16x8*)(&Ct[od * 136 + k8 * 8]);
      *(f16x8*)(C + ((size_t)(bb_ * 1024 + n0 + od)) * 2048 + key0 + k8 * 8) = v;
    }
  } else {
    float* C = (float*)Cv + (size_t)bz * scz;
#pragma unroll
    for (int ni = 0; ni < 4; ni++) {
      int col = n0 + wn + ni * 16 + lr;
#pragma unroll
      for (int mi = 0; mi < 4; mi++)
#pragma unroll
        for (int i = 0; i < 4; i++) {
          int row = m0 + wm + mi * 16 + lg * 4 + i;
          C[(size_t)row * ldc + col] = acc[mi][ni][i];
        }
    }
  }
}

// ---------------- masked softmax, one wave per row, P=f16 in place ----------------
// Sb: rows of 2048 f32 (stride 8192 B). After: first 4096 B of each row = 2048 f16 P.
__global__ __launch_bounds__(256) void k_softmax(char* Sb, const int* __restrict__ mask) {
  const int row = blockIdx.x * 4 + (threadIdx.x >> 6);
  const int lane = threadIdx.x & 63;
  const int b = row >> 11;  // batch within chunk
  float* Srow = (float*)(Sb + (size_t)row * (LSEQ * 4));
  const int* mrow = mask + b * LSEQ;

  float v[32];
  float m = -3e38f;
#pragma unroll
  for (int j = 0; j < 8; j++) {
    const int p = j * 256 + lane * 4;
    float4 s = *(const float4*)(Srow + p);
    int4 mk = *(const int4*)(mrow + p);
    float a0 = mk.x ? -3e38f : s.x;
    float a1 = mk.y ? -3e38f : s.y;
    float a2 = mk.z ? -3e38f : s.z;
    float a3 = mk.w ? -3e38f : s.w;
    v[j * 4 + 0] = a0;
    v[j * 4 + 1] = a1;
    v[j * 4 + 2] = a2;
    v[j * 4 + 3] = a3;
    m = fmaxf(m, fmaxf(fmaxf(a0, a1), fmaxf(a2, a3)));
  }
#pragma unroll
  for (int off = 32; off; off >>= 1) m = fmaxf(m, __shfl_xor(m, off));
  float l = 0.f;
#pragma unroll
  for (int j = 0; j < 32; j++) {
    float p = __expf(v[j] - m);  // masked: exp(-3e38 - m) underflows to 0
    v[j] = p;
    l += p;
  }
#pragma unroll
  for (int off = 32; off; off >>= 1) l += __shfl_xor(l, off);
  const float inv = 1.f / l;
  f16* Prow = (f16*)Srow;
#pragma unroll
  for (int j = 0; j < 8; j++) {
    const int p = j * 256 + lane * 4;
    f16x4 o;
    o[0] = (f16)(v[j * 4 + 0] * inv);
    o[1] = (f16)(v[j * 4 + 1] * inv);
    o[2] = (f16)(v[j * 4 + 2] * inv);
    o[3] = (f16)(v[j * 4 + 3] * inv);
    *(f16x4*)(Prow + p) = o;
  }
}

extern "C" void kernel_launch(void* const* d_in, const int* in_sizes, int n_in,
                              void* d_out, int out_size, void* d_ws, size_t ws_size,
                              hipStream_t stream) {
  const float* x = (const float*)d_in[0];
  const float* y = (const float*)d_in[1];
  const int* ym = (const int*)d_in[2];
  const float* Wq = (const float*)d_in[3];
  const float* bq = (const float*)d_in[4];
  const float* Wk = (const float*)d_in[5];
  const float* bk = (const float*)d_in[6];
  const float* Wv = (const float*)d_in[7];
  const float* bv = (const float*)d_in[8];
  float* out = (float*)d_out;

  char* w = (char*)d_ws;
  const size_t SZ_T = (size_t)NB * LSEQ * DIM * sizeof(f16);            // 64 MB
  const size_t SZ_SC = (size_t)CHB * LSEQ * LSEQ * sizeof(float);       // 128 MB
  const size_t SZ_W = (size_t)DIM * DIM * sizeof(f16);                  // 2 MB

  // Peak footprint 326 MB (same as round-1 proven layout):
  // [0,128M): xh+yh during projections, then S chunk during attention
  // [128M,320M): Qh, Kh, Vt   [320M,326M): Wqt, Wkt, Wvt
  f16* xh = (f16*)w;
  f16* yh = (f16*)(w + SZ_T);
  char* Sb = w;
  f16* Qh = (f16*)(w + SZ_SC);
  f16* Kh = (f16*)(w + SZ_SC + SZ_T);
  f16* Vt = (f16*)(w + SZ_SC + 2 * SZ_T);
  f16* Wqt = (f16*)(w + SZ_SC + 3 * SZ_T);
  f16* Wkt = (f16*)(w + SZ_SC + 3 * SZ_T + SZ_W);
  f16* Wvt = (f16*)(w + SZ_SC + 3 * SZ_T + 2 * SZ_W);

  k_cvt<<<2048, 256, 0, stream>>>(x, xh, NB * LSEQ * DIM / 8);
  k_cvt<<<2048, 256, 0, stream>>>(y, yh, NB * LSEQ * DIM / 8);
  dim3 wt(32, 32);
  k_wtrans<<<wt, 256, 0, stream>>>(Wq, Wqt);
  k_wtrans<<<wt, 256, 0, stream>>>(Wk, Wkt);
  k_wtrans<<<wt, 256, 0, stream>>>(Wv, Wvt);

  dim3 gp(256, 8, 1);
  k_mm<0, 32><<<gp, 256, 0, stream>>>(xh, 1024, 0, Wqt, 1024, 0, bq, Qh, 1024, 0);
  k_mm<0, 32><<<gp, 256, 0, stream>>>(yh, 1024, 0, Wkt, 1024, 0, bk, Kh, 1024, 0);
  k_mm<1, 32><<<gp, 256, 0, stream>>>(yh, 1024, 0, Wvt, 1024, 0, bv, Vt, 0, 0);

  for (int c = 0; c < NB / CHB; ++c) {
    const size_t boff = (size_t)c * CHB;
    // S[b] = Q[b] * K[b]^T   (f32, ldc=2048)
    dim3 gq(16, 16, CHB);
    k_mm<2, 32><<<gq, 256, 0, stream>>>(Qh + boff * LSEQ * DIM, 1024, (size_t)LSEQ * DIM,
                                        Kh + boff * LSEQ * DIM, 1024, (size_t)LSEQ * DIM,
                                        nullptr, Sb, 2048, (size_t)LSEQ * LSEQ);
    // masked softmax rows -> P f16 in place
    k_softmax<<<CHB * LSEQ / 4, 256, 0, stream>>>(Sb, ym + boff * LSEQ);
    // out[b] = P[b] (lda=4096 f16) * Vt[b]^T
    dim3 gv(16, 8, CHB);
    k_mm<2, 64><<<gv, 256, 0, stream>>>((const f16*)Sb, 4096, (size_t)LSEQ * 4096,
                                        Vt + boff * DIM * LSEQ, 2048, (size_t)DIM * LSEQ,
                                        nullptr, out + boff * LSEQ * DIM, 1024,
                                        (size_t)LSEQ * DIM);
  }
}